// Round 2
// 9790.997 us; speedup vs baseline: 1.3511x; 1.3511x over previous
//
#include <hip/hip_runtime.h>

typedef __bf16 bf16;
typedef __bf16 bf16x4 __attribute__((ext_vector_type(4)));
typedef __bf16 bf16x8 __attribute__((ext_vector_type(8)));
typedef float f32x4 __attribute__((ext_vector_type(4)));
typedef unsigned int u32;
typedef unsigned long long u64;

#define T_STEPS 1024
#define BATCH 128
#define DIM 256      // D
#define HID 512      // H
#define NB 128       // 4 batch-groups x 32 col-groups
#define GC 32        // col groups (blocks per batch-group barrier)
#define MROWS 32     // batches per block (2 M-tiles per wave)
#define FLAGS_BYTES 16384

__device__ __forceinline__ f32x4 mfma_bf16(bf16x8 a, bf16x8 b, f32x4 c) {
  return __builtin_amdgcn_mfma_f32_16x16x32_bf16(a, b, c, 0, 0, 0);
}
__device__ __forceinline__ float fast_sigmoid(float v) {
  return __builtin_amdgcn_rcpf(1.f + __expf(-v));
}
__device__ __forceinline__ float fast_tanh(float v) {
  return 2.f * __builtin_amdgcn_rcpf(1.f + __expf(-2.f * v)) - 1.f;
}
__device__ __forceinline__ bf16x8 cvt8(const float* p) {
  float4 a = *(const float4*)p;
  float4 b = *(const float4*)(p + 4);
  bf16x8 r;
  r[0] = (bf16)a.x; r[1] = (bf16)a.y; r[2] = (bf16)a.z; r[3] = (bf16)a.w;
  r[4] = (bf16)b.x; r[5] = (bf16)b.y; r[6] = (bf16)b.z; r[7] = (bf16)b.w;
  return r;
}
__device__ __forceinline__ u32 pack_bf16x2(float a, float b) {
  unsigned short lo = __builtin_bit_cast(unsigned short, (bf16)a);
  unsigned short hi = __builtin_bit_cast(unsigned short, (bf16)b);
  return (u32)lo | ((u32)hi << 16);
}
__device__ __forceinline__ bf16x8 combine(u64 lo, u64 hi) {
  bf16x4 l4 = __builtin_bit_cast(bf16x4, lo);
  bf16x4 h4 = __builtin_bit_cast(bf16x4, hi);
  bf16x8 r;
  r[0] = l4[0]; r[1] = l4[1]; r[2] = l4[2]; r[3] = l4[3];
  r[4] = h4[0]; r[5] = h4[1]; r[6] = h4[2]; r[7] = h4[3];
  return r;
}
__device__ __forceinline__ u64 ld_agent(const u64* p) {
  return __hip_atomic_load(p, __ATOMIC_RELAXED, __HIP_MEMORY_SCOPE_AGENT);
}

// group wait: lanes 0..31 poll the 32 flags of this batch-group (dup on 32..63)
__device__ __forceinline__ void wait_group(const u32* flags, int gbase, int lane,
                                           u32 target) {
  const u32* my = flags + (size_t)(gbase + (lane & 31)) * 16;
  u32 f = __hip_atomic_load(my, __ATOMIC_RELAXED, __HIP_MEMORY_SCOPE_AGENT);
  while (!__all(f >= target)) {
    __builtin_amdgcn_s_sleep(1);
    f = __hip_atomic_load(my, __ATOMIC_RELAXED, __HIP_MEMORY_SCOPE_AGENT);
  }
}

// wait for all 128 block flags (final fc)
__device__ __forceinline__ void wait_all128(const u32* flags, int lane, u32 target) {
  const u32* p0 = flags + (size_t)lane * 16;
  const u32* p1 = flags + (size_t)(64 + lane) * 16;
  u32 a = __hip_atomic_load(p0, __ATOMIC_RELAXED, __HIP_MEMORY_SCOPE_AGENT);
  u32 b = __hip_atomic_load(p1, __ATOMIC_RELAXED, __HIP_MEMORY_SCOPE_AGENT);
  while (!__all((a >= target) && (b >= target))) {
    __builtin_amdgcn_s_sleep(1);
    a = __hip_atomic_load(p0, __ATOMIC_RELAXED, __HIP_MEMORY_SCOPE_AGENT);
    b = __hip_atomic_load(p1, __ATOMIC_RELAXED, __HIP_MEMORY_SCOPE_AGENT);
  }
}

// ws layout: [0 .. 16383] flags[128] (one per 64B line), [16384 ..] hbuf[2][128*512] bf16
//
// Partition: bid = bg*32 + cg. Block owns batches [bg*32, bg*32+32) x h-cols
// [cg*16, cg*16+16). Per wave w: same 32 batches (2 M-tiles) x 4 h-cols
// (16 gate rows: gate g = nn>>2, sub = nn&3 -> hcol = cg*16 + w*4 + sub).
// Recurrence sync is PER batch-group (32 blocks), not global.
// Weights (Wh 16 frags + Wx 8 frags per lane) live in REGISTERS: at
// launch_bounds(256,1) each wave has a full 512-VGPR budget (1 wave/SIMD).
__global__ __launch_bounds__(256, 1) void lstm_persist(
    const float* __restrict__ x, const float* __restrict__ Wx,
    const float* __restrict__ bx, const float* __restrict__ Wh,
    const float* __restrict__ bh, const float* __restrict__ Wfc,
    const float* __restrict__ bfc, float* __restrict__ out,
    u32* flags, bf16* hbuf) {
  const int tid = threadIdx.x;
  const int bid = blockIdx.x;
  const int wave = tid >> 6;
  const int lane = tid & 63;
  const int n = lane & 15;      // MFMA column / A-row selector
  const int quad = lane >> 4;   // k-chunk selector
  const int sub = n & 3;        // col-sub within 4-group
  const int bg = bid >> 5;      // batch group 0..3
  const int cg = bid & 31;      // col group 0..31
  const int mbase = bg * MROWS; // first batch row of this block

  __shared__ bf16 lds_h[32][520];  // staged h rows for this batch group (33 KB)

  // ---- this lane's gate row: R = gate*HID + hcol ----
  const int Rl = (n >> 2) * HID + cg * 16 + wave * 4 + sub;
  const float bias = bx[Rl] + bh[Rl];
  const f32x4 bv = {bias, bias, bias, bias};

  // ---- weight fragments in registers (fixed for all 1024 steps) ----
  bf16x8 whf[16];
#pragma unroll
  for (int k = 0; k < 16; ++k)
    whf[k] = cvt8(Wh + (size_t)Rl * HID + quad * 8 + k * 32);
  bf16x8 wxf[8];
#pragma unroll
  for (int k = 0; k < 8; ++k)
    wxf[k] = cvt8(Wx + (size_t)Rl * DIM + quad * 8 + k * 32);

  float cst[2][4];
#pragma unroll
  for (int a = 0; a < 2; ++a)
#pragma unroll
    for (int r = 0; r < 4; ++r) cst[a][r] = 0.f;

  const int qb = lane & 48;
  const int srcf = qb | (4 + sub);
  const int srcg = qb | (8 + sub);
  const int srco = qb | (12 + sub);

  // staging map: thread -> h row (tid&31), two consecutive 64B chunks (128B run)
  const int srow = tid & 31;
  const int schunk = (tid >> 5) * 2;  // 0,2,..,14 (chunk = 32 elems = 64B)

  for (int t = 0; t < T_STEPS; ++t) {
    const bf16* hrd = hbuf + (t & 1) * (BATCH * HID);
    bf16* hwr = hbuf + ((t + 1) & 1) * (BATCH * HID);

    f32x4 acc0 = bv, acc1 = bv;

    // ---- x_t @ Wx^T first: independent of other blocks, overlaps the wait ----
    const float* x0p = x + (size_t)((mbase + n) * 1024 + t) * DIM + quad * 8;
    const float* x1p = x0p + (size_t)16 * 1024 * DIM;
#pragma unroll
    for (int k = 0; k < 8; ++k) {
      bf16x8 A0 = cvt8(x0p + k * 32);
      bf16x8 A1 = cvt8(x1p + k * 32);
      acc0 = mfma_bf16(A0, wxf[k], acc0);
      acc1 = mfma_bf16(A1, wxf[k], acc1);
    }

    // ---- wait until our 32-block group finished step t-1 (h[t&1] rows ready) ----
    wait_group(flags, bg * GC, lane, (u32)t);

    // ---- cooperative gather of our 32 h rows (32 KB) into LDS:
    //      16 agent u64 loads per thread = one 128B contiguous run; each 64B
    //      line fetched exactly once per block (512 lines total) ----
    {
      const u64* src = (const u64*)hrd + (size_t)(mbase + srow) * (HID / 4) + schunk * 8;
      u64 hv[16];
#pragma unroll
      for (int j = 0; j < 16; ++j) hv[j] = ld_agent(src + j);
      u64* dst = (u64*)(&lds_h[srow][schunk * 32]);
#pragma unroll
      for (int j = 0; j < 16; ++j) dst[j] = hv[j];
    }
    __syncthreads();  // lds_h ready (prev step's readers passed publish barrier)

    // ---- h @ Wh^T: A from LDS, B from registers ----
#pragma unroll
    for (int k = 0; k < 16; ++k) {
      bf16x8 A0 = *(const bf16x8*)(&lds_h[n][quad * 8 + k * 32]);
      bf16x8 A1 = *(const bf16x8*)(&lds_h[16 + n][quad * 8 + k * 32]);
      acc0 = mfma_bf16(A0, whf[k], acc0);
      acc1 = mfma_bf16(A1, whf[k], acc1);
    }

    // ---- gate nonlinearities + cell update ----
    f32x4 accs[2] = {acc0, acc1};
#pragma unroll
    for (int mt = 0; mt < 2; ++mt) {
#pragma unroll
      for (int r = 0; r < 4; ++r) {
        float v = accs[mt][r];
        float s = fast_sigmoid(v);
        float th = fast_tanh(v);
        float pv = (n >= 8 && n < 12) ? th : s;  // g-gate lanes: tanh
        float fv = __shfl(pv, srcf, 64);
        float gv = __shfl(pv, srcg, 64);
        float ov = __shfl(pv, srco, 64);
        float cn = cst[mt][r] * fv + pv * gv;    // pv == i on lanes n<4
        float hn = ov * fast_tanh(cn);
        cst[mt][r] = cn;
        // pack the 4 adjacent h-cols of this quad into one 8B store from n==0
        float h1 = __shfl(hn, qb | 1, 64);
        float h2 = __shfl(hn, qb | 2, 64);
        float h3 = __shfl(hn, qb | 3, 64);
        if (n == 0) {
          int m = mbase + mt * 16 + quad * 4 + r;
          int c0 = cg * 16 + wave * 4;
          u64 pk = (u64)pack_bf16x2(hn, h1) | ((u64)pack_bf16x2(h2, h3) << 32);
          __hip_atomic_store((u64*)(hwr + (size_t)m * HID + c0), pk,
                             __ATOMIC_RELAXED, __HIP_MEMORY_SCOPE_AGENT);
          if (t == T_STEPS - 1) {
            float4 o4 = {hn, h1, h2, h3};
            *(float4*)(out + (size_t)m * HID + c0) = o4;
          }
        }
      }
    }

    // ---- publish: one flag per block, own cache line, no RMW, no reset.
    // __syncthreads drains every wave's vmcnt -> all h-stores of this block
    // are globally visible before tid0's flag store issues. ----
    __syncthreads();
    if (tid == 0) {
      __hip_atomic_store(flags + (size_t)bid * 16, (u32)(t + 1),
                         __ATOMIC_RELAXED, __HIP_MEMORY_SCOPE_AGENT);
    }
  }

  // ---- final fc: out2[b][o] = hT @ Wfc^T + bfc (blocks 0..7, 16 cols each) ----
  if (bid < 8) {
    wait_all128(flags, lane, (u32)T_STEPS);  // all blocks' final h written
    float* out2 = out + BATCH * HID;
    int col = bid * 16 + n;
    float bcv = bfc[col];
#pragma unroll
    for (int mt = 0; mt < 2; ++mt) {
      int mb = wave * 32 + mt * 16;
      f32x4 a4 = {bcv, bcv, bcv, bcv};
      const u64* ar = (const u64*)hbuf + ((mb + n) * HID) / 4 + quad * 2;  // hT = buffer 0
      const float* br = Wfc + col * HID + quad * 8;
#pragma unroll
      for (int k = 0; k < HID; k += 32) {
        bf16x8 A = combine(ld_agent(ar + k / 4), ld_agent(ar + k / 4 + 1));
        bf16x8 B = cvt8(br + k);
        a4 = mfma_bf16(A, B, a4);
      }
#pragma unroll
      for (int r = 0; r < 4; ++r) {
        out2[(mb + quad * 4 + r) * 128 + col] = a4[r];
      }
    }
  }
}

extern "C" void kernel_launch(void* const* d_in, const int* in_sizes, int n_in,
                              void* d_out, int out_size, void* d_ws, size_t ws_size,
                              hipStream_t stream) {
  (void)in_sizes; (void)n_in; (void)out_size; (void)ws_size;
  const float* x   = (const float*)d_in[0];
  const float* Wx  = (const float*)d_in[2];
  const float* bx  = (const float*)d_in[3];
  const float* Wh  = (const float*)d_in[4];
  const float* bh  = (const float*)d_in[5];
  const float* Wfc = (const float*)d_in[8];
  const float* bfc = (const float*)d_in[9];
  float* out = (float*)d_out;
  u32* flags = (u32*)d_ws;
  bf16* hbuf = (bf16*)((char*)d_ws + FLAGS_BYTES);

  // zero flags + both h buffers (h0 = 0); ws is re-poisoned before every launch
  hipMemsetAsync(d_ws, 0, FLAGS_BYTES + 2 * BATCH * HID * sizeof(bf16), stream);
  lstm_persist<<<dim3(NB), dim3(256), 0, stream>>>(x, Wx, bx, Wh, bh, Wfc, bfc,
                                                   out, flags, hbuf);
}

// Round 4
// 5805.291 us; speedup vs baseline: 2.2788x; 1.6866x over previous
//
#include <hip/hip_runtime.h>

typedef __bf16 bf16;
typedef __bf16 bf16x4 __attribute__((ext_vector_type(4)));
typedef __bf16 bf16x8 __attribute__((ext_vector_type(8)));
typedef float f32x4 __attribute__((ext_vector_type(4)));
typedef unsigned int u32;
typedef unsigned long long u64;

#define T_STEPS 1024
#define BATCH 128
#define DIM 256      // D
#define HID 512      // H
#define NB 128       // 8 batch-groups x 16 col-groups
#define NGRP 8       // batch groups: bg = bid & 7 (XCD-aligned if rr mapping)
#define GB 16        // batches per group
#define FLAGS_BYTES 16384  // 128 block flags, one 64B line each

__device__ __forceinline__ f32x4 mfma_bf16(bf16x8 a, bf16x8 b, f32x4 c) {
  return __builtin_amdgcn_mfma_f32_16x16x32_bf16(a, b, c, 0, 0, 0);
}
__device__ __forceinline__ float fast_sigmoid(float v) {
  return __builtin_amdgcn_rcpf(1.f + __expf(-v));
}
__device__ __forceinline__ float fast_tanh(float v) {
  return 2.f * __builtin_amdgcn_rcpf(1.f + __expf(-2.f * v)) - 1.f;
}
__device__ __forceinline__ bf16x8 cvt8(const float* p) {
  float4 a = *(const float4*)p;
  float4 b = *(const float4*)(p + 4);
  bf16x8 r;
  r[0] = (bf16)a.x; r[1] = (bf16)a.y; r[2] = (bf16)a.z; r[3] = (bf16)a.w;
  r[4] = (bf16)b.x; r[5] = (bf16)b.y; r[6] = (bf16)b.z; r[7] = (bf16)b.w;
  return r;
}
__device__ __forceinline__ u32 pack_bf16x2(float a, float b) {
  unsigned short lo = __builtin_bit_cast(unsigned short, (bf16)a);
  unsigned short hi = __builtin_bit_cast(unsigned short, (bf16)b);
  return (u32)lo | ((u32)hi << 16);
}
__device__ __forceinline__ bf16x8 combine(u64 lo, u64 hi) {
  bf16x4 l4 = __builtin_bit_cast(bf16x4, lo);
  bf16x4 h4 = __builtin_bit_cast(bf16x4, hi);
  bf16x8 r;
  r[0] = l4[0]; r[1] = l4[1]; r[2] = l4[2]; r[3] = l4[3];
  r[4] = h4[0]; r[5] = h4[1]; r[6] = h4[2]; r[7] = h4[3];
  return r;
}
__device__ __forceinline__ u64 ld_agent(const u64* p) {
  return __hip_atomic_load(p, __ATOMIC_RELAXED, __HIP_MEMORY_SCOPE_AGENT);
}

// group wait: lane i polls the flag of group-block (i&15); 4x redundant over 64 lanes
__device__ __forceinline__ void wait_group(const u32* flags, int bg, int lane,
                                           u32 target) {
  const int bid_p = ((lane & 15) * NGRP) + bg;  // block (lane&15) of this group
  const u32* my = flags + (size_t)bid_p * 16;
  u32 f = __hip_atomic_load(my, __ATOMIC_RELAXED, __HIP_MEMORY_SCOPE_AGENT);
  while (!__all(f >= target)) {
    __builtin_amdgcn_s_sleep(1);
    f = __hip_atomic_load(my, __ATOMIC_RELAXED, __HIP_MEMORY_SCOPE_AGENT);
  }
}

// wait for all 128 block flags (final fc)
__device__ __forceinline__ void wait_all128(const u32* flags, int lane, u32 target) {
  const u32* p0 = flags + (size_t)lane * 16;
  const u32* p1 = flags + (size_t)(64 + lane) * 16;
  u32 a = __hip_atomic_load(p0, __ATOMIC_RELAXED, __HIP_MEMORY_SCOPE_AGENT);
  u32 b = __hip_atomic_load(p1, __ATOMIC_RELAXED, __HIP_MEMORY_SCOPE_AGENT);
  while (!__all((a >= target) && (b >= target))) {
    __builtin_amdgcn_s_sleep(1);
    a = __hip_atomic_load(p0, __ATOMIC_RELAXED, __HIP_MEMORY_SCOPE_AGENT);
    b = __hip_atomic_load(p1, __ATOMIC_RELAXED, __HIP_MEMORY_SCOPE_AGENT);
  }
}

// ws layout: [0 .. 16383] flags[128] (one per 64B line), [16384 ..] hbuf[2][128*512] bf16
//
// Partition: bg = bid & 7, cg = bid >> 3. Block owns batches [bg*16, bg*16+16)
// x h-cols [cg*32, cg*32+32). Per wave w: 16 batches (1 M-tile) x 8 h-cols
// (2 N-tiles nt: col = cg*32 + w*8 + nt*4 + sub, gate = n>>2).
// Weights in REGISTERS (2x16 + 2x8 bf16x8 frags = 192 VGPR); full 512-VGPR
// budget at 1 wave/SIMD. Sync protocol is the round-2 HW-validated one:
// block-level flags, publish = __syncthreads (drains all waves' vmem) + tid0
// flag store; group-local wait. Single LDS h-tile, double global h-buffer.
__global__ __launch_bounds__(256, 1) void lstm_persist(
    const float* __restrict__ x, const float* __restrict__ Wx,
    const float* __restrict__ bx, const float* __restrict__ Wh,
    const float* __restrict__ bh, const float* __restrict__ Wfc,
    const float* __restrict__ bfc, float* __restrict__ out,
    u32* flags, bf16* hbuf) {
  const int tid = threadIdx.x;
  const int bid = blockIdx.x;
  const int wave = tid >> 6;
  const int lane = tid & 63;
  const int n = lane & 15;      // MFMA column / A-row selector
  const int quad = lane >> 4;   // k-chunk selector
  const int sub = n & 3;        // col-sub within 4-group
  const int bg = bid & 7;       // batch group 0..7 (XCD-aligned if rr mapping)
  const int cg = bid >> 3;      // col group 0..15
  const int mbase = bg * GB;    // first batch row of this block

  __shared__ bf16 lds_h[16][520];  // staged h tile for this group (16.6 KB)

  // ---- this lane's two gate rows (N-tiles nt=0,1): R = gate*HID + hcol ----
  const int R0 = (n >> 2) * HID + cg * 32 + wave * 8 + sub;
  const int R1 = R0 + 4;
  const float bias0 = bx[R0] + bh[R0];
  const float bias1 = bx[R1] + bh[R1];
  const f32x4 bv0 = {bias0, bias0, bias0, bias0};
  const f32x4 bv1 = {bias1, bias1, bias1, bias1};

  // ---- weight fragments in registers (fixed for all 1024 steps) ----
  bf16x8 whf0[16], whf1[16];
#pragma unroll
  for (int k = 0; k < 16; ++k) {
    whf0[k] = cvt8(Wh + (size_t)R0 * HID + quad * 8 + k * 32);
    whf1[k] = cvt8(Wh + (size_t)R1 * HID + quad * 8 + k * 32);
  }
  bf16x8 wxf0[8], wxf1[8];
#pragma unroll
  for (int k = 0; k < 8; ++k) {
    wxf0[k] = cvt8(Wx + (size_t)R0 * DIM + quad * 8 + k * 32);
    wxf1[k] = cvt8(Wx + (size_t)R1 * DIM + quad * 8 + k * 32);
  }

  float cst[2][4];
#pragma unroll
  for (int a = 0; a < 2; ++a)
#pragma unroll
    for (int r = 0; r < 4; ++r) cst[a][r] = 0.f;

  const int qb = lane & 48;
  const int srcf = qb | (4 + sub);
  const int srcg = qb | (8 + sub);
  const int srco = qb | (12 + sub);

  // gather map: thread -> (row 0..15, one 64B chunk 0..15): exactly 1 line/thread
  const int grow = tid >> 4;
  const int gchunk = tid & 15;

  __syncthreads();  // weights loaded (not strictly needed; cheap)

  for (int t = 0; t < T_STEPS; ++t) {
    const bf16* hrd = hbuf + (t & 1) * (BATCH * HID);
    bf16* hwr = hbuf + ((t + 1) & 1) * (BATCH * HID);

    f32x4 acc0 = bv0, acc1 = bv1;

    // ---- x_t @ Wx^T first: independent of other blocks, hides flag latency;
    // with bg = bid&7 all 16 blocks of a group share these x rows in one L2 ----
    const float* x0p = x + (size_t)((mbase + n) * 1024 + t) * DIM + quad * 8;
#pragma unroll
    for (int k = 0; k < 8; ++k) {
      bf16x8 A = cvt8(x0p + k * 32);
      acc0 = mfma_bf16(A, wxf0[k], acc0);
      acc1 = mfma_bf16(A, wxf1[k], acc1);
    }

    // ---- wait until all 16 blocks of our group finished step t-1 ----
    wait_group(flags, bg, lane, (u32)t);

    // ---- cooperative gather of our 16 h rows (16 KB) into LDS:
    //      one contiguous 64B line per thread, each line fetched once ----
    {
      const u64* src = (const u64*)hrd + (size_t)(mbase + grow) * (HID / 4) + gchunk * 8;
      u64 hv[8];
#pragma unroll
      for (int j = 0; j < 8; ++j) hv[j] = ld_agent(src + j);
      u64* dst = (u64*)(&lds_h[grow][gchunk * 32]);
#pragma unroll
      for (int j = 0; j < 8; ++j) dst[j] = hv[j];
    }
    __syncthreads();  // lds_h ready (prev step's readers passed publish barrier)

    // ---- h @ Wh^T: A from LDS (shared across nt), B from registers ----
#pragma unroll
    for (int k = 0; k < 16; ++k) {
      bf16x8 A = *(const bf16x8*)(&lds_h[n][quad * 8 + k * 32]);
      acc0 = mfma_bf16(A, whf0[k], acc0);
      acc1 = mfma_bf16(A, whf1[k], acc1);
    }

    // ---- gate nonlinearities + cell update ----
    f32x4 accs[2] = {acc0, acc1};
#pragma unroll
    for (int nt = 0; nt < 2; ++nt) {
#pragma unroll
      for (int r = 0; r < 4; ++r) {
        float v = accs[nt][r];
        float s = fast_sigmoid(v);
        float th = fast_tanh(v);
        float pv = (n >= 8 && n < 12) ? th : s;  // g-gate lanes: tanh
        float fv = __shfl(pv, srcf, 64);
        float gv = __shfl(pv, srcg, 64);
        float ov = __shfl(pv, srco, 64);
        float cn = cst[nt][r] * fv + pv * gv;    // pv == i on lanes n<4
        float hn = ov * fast_tanh(cn);
        cst[nt][r] = cn;
        // pack the 4 adjacent h-cols of this nt into one 8B store from n==0
        float h1 = __shfl(hn, qb | 1, 64);
        float h2 = __shfl(hn, qb | 2, 64);
        float h3 = __shfl(hn, qb | 3, 64);
        if (n == 0) {
          int m = mbase + quad * 4 + r;
          int c0 = cg * 32 + wave * 8 + nt * 4;
          u64 pk = (u64)pack_bf16x2(hn, h1) | ((u64)pack_bf16x2(h2, h3) << 32);
          __hip_atomic_store((u64*)(hwr + (size_t)m * HID + c0), pk,
                             __ATOMIC_RELAXED, __HIP_MEMORY_SCOPE_AGENT);
          if (t == T_STEPS - 1) {
            float4 o4 = {hn, h1, h2, h3};
            *(float4*)(out + (size_t)m * HID + c0) = o4;
          }
        }
      }
    }

    // ---- publish: one flag per block, own cache line, no RMW, no reset.
    // __syncthreads drains every wave's vmcnt -> all h-stores of this block
    // are globally visible before tid0's flag store issues. ----
    __syncthreads();
    if (tid == 0) {
      __hip_atomic_store(flags + (size_t)bid * 16, (u32)(t + 1),
                         __ATOMIC_RELAXED, __HIP_MEMORY_SCOPE_AGENT);
    }
  }

  // ---- final fc: out2[b][o] = hT @ Wfc^T + bfc (blocks 0..7, 16 cols each) ----
  if (bid < 8) {
    wait_all128(flags, lane, (u32)T_STEPS);  // all blocks' final h written
    float* out2 = out + BATCH * HID;
    int col = bid * 16 + n;
    float bcv = bfc[col];
#pragma unroll
    for (int mt = 0; mt < 2; ++mt) {
      int mb = wave * 32 + mt * 16;
      f32x4 a4 = {bcv, bcv, bcv, bcv};
      const u64* ar = (const u64*)hbuf + ((mb + n) * HID) / 4 + quad * 2;  // hT = buffer 0
      const float* br = Wfc + col * HID + quad * 8;
#pragma unroll
      for (int k = 0; k < HID; k += 32) {
        bf16x8 A = combine(ld_agent(ar + k / 4), ld_agent(ar + k / 4 + 1));
        bf16x8 B = cvt8(br + k);
        a4 = mfma_bf16(A, B, a4);
      }
#pragma unroll
      for (int r = 0; r < 4; ++r) {
        out2[(mb + quad * 4 + r) * 128 + col] = a4[r];
      }
    }
  }
}

extern "C" void kernel_launch(void* const* d_in, const int* in_sizes, int n_in,
                              void* d_out, int out_size, void* d_ws, size_t ws_size,
                              hipStream_t stream) {
  (void)in_sizes; (void)n_in; (void)out_size; (void)ws_size;
  const float* x   = (const float*)d_in[0];
  const float* Wx  = (const float*)d_in[2];
  const float* bx  = (const float*)d_in[3];
  const float* Wh  = (const float*)d_in[4];
  const float* bh  = (const float*)d_in[5];
  const float* Wfc = (const float*)d_in[8];
  const float* bfc = (const float*)d_in[9];
  float* out = (float*)d_out;
  u32* flags = (u32*)d_ws;
  bf16* hbuf = (bf16*)((char*)d_ws + FLAGS_BYTES);

  // zero flags + both h buffers (h0 = 0); ws is re-poisoned before every launch
  hipMemsetAsync(d_ws, 0, FLAGS_BYTES + 2 * BATCH * HID * sizeof(bf16), stream);
  lstm_persist<<<dim3(NB), dim3(256), 0, stream>>>(x, Wx, bx, Wh, bh, Wfc, bfc,
                                                   out, flags, hbuf);
}